// Round 5
// baseline (316.390 us; speedup 1.0000x reference)
//
#include <hip/hip_runtime.h>

typedef short bh8 __attribute__((ext_vector_type(8)));
typedef short bh4 __attribute__((ext_vector_type(4)));
typedef float f4 __attribute__((ext_vector_type(4)));
typedef unsigned int u32;
typedef u32 u32x2 __attribute__((ext_vector_type(2)));

#if __has_builtin(__builtin_amdgcn_exp2f)
#define EXP2(x) __builtin_amdgcn_exp2f(x)
#else
#define EXP2(x) exp2f(x)
#endif

__device__ __forceinline__ short f2bf(float f) {
  unsigned u = __float_as_uint(f);
  u += 0x7FFFu + ((u >> 16) & 1u);
  return (short)(u >> 16);
}

__device__ __forceinline__ void async16(const void* g, void* l) {
  __builtin_amdgcn_global_load_lds((const __attribute__((address_space(1))) void*)g,
                                   (__attribute__((address_space(3))) void*)l, 16, 0, 0);
}

// ---------------- fp32 -> bf16 convert (x) ----------------
__global__ void cvt_kernel(const float* __restrict__ in, short* __restrict__ out, int n4) {
  int i = blockIdx.x * blockDim.x + threadIdx.x;
  if (i < n4) {
    f4 v = *(const f4*)(in + (size_t)i * 4);
    bh4 o;
    o[0] = f2bf(v[0]); o[1] = f2bf(v[1]); o[2] = f2bf(v[2]); o[3] = f2bf(v[3]);
    *(bh4*)(out + (size_t)i * 4) = o;
  }
}

// ---------------- fused weight converts (Wq,Wk,Wv,Wo -> contiguous bf16) ----------------
__global__ void cvt_w4(const float* __restrict__ w0, const float* __restrict__ w1,
                       const float* __restrict__ w2, const float* __restrict__ w3,
                       short* __restrict__ out, int n4_per) {
  const float* in = blockIdx.y == 0 ? w0 : blockIdx.y == 1 ? w1 : blockIdx.y == 2 ? w2 : w3;
  short* o = out + (size_t)blockIdx.y * (size_t)n4_per * 4;
  int i = blockIdx.x * blockDim.x + threadIdx.x;
  if (i < n4_per) {
    f4 v = *(const f4*)(in + (size_t)i * 4);
    bh4 q;
    q[0] = f2bf(v[0]); q[1] = f2bf(v[1]); q[2] = f2bf(v[2]); q[3] = f2bf(v[3]);
    *(bh4*)(o + (size_t)i * 4) = q;
  }
}

// ---------------- GEMM core (128x128 tile, BK=32, 4 waves) ----------------
// C[m][n] = (sum_k A[m][k]*Bw[n][k] + bias) * scale; BROW: bias indexed by row (for V^T).
template <typename OutT, bool BROW>
__device__ __forceinline__ void gemm_body(const short* __restrict__ A, const short* __restrict__ Bw,
                                          const float* __restrict__ bias, OutT* __restrict__ C,
                                          int m0, int n0, int N, int K, float scale,
                                          short* a_lds, short* b_lds) {
  const int t = threadIdx.x;
  const int lane = t & 63, wave = t >> 6, quad = lane >> 4, l15 = lane & 15;
  const int mw = (wave >> 1) * 64, nw = (wave & 1) * 64;

  f4 acc[4][4];
#pragma unroll
  for (int i = 0; i < 4; ++i)
#pragma unroll
    for (int j = 0; j < 4; ++j) acc[i][j] = (f4){0.f, 0.f, 0.f, 0.f};

  for (int k0 = 0; k0 < K; k0 += 32) {
#pragma unroll
    for (int i = 0; i < 2; ++i) {
      int c = i * 256 + t;
      int m = c >> 2;
      int kq = (c & 3) ^ ((m >> 1) & 3);
      const short* ga = A + (size_t)(m0 + m) * K + k0 + kq * 8;
      const short* gb = Bw + (size_t)(n0 + m) * K + k0 + kq * 8;
      async16(ga, (char*)a_lds + (i * 256 + wave * 64) * 16);
      async16(gb, (char*)b_lds + (i * 256 + wave * 64) * 16);
    }
    __syncthreads();
    bh8 af[4], bfr[4];
#pragma unroll
    for (int ms = 0; ms < 4; ++ms) {
      int m = mw + ms * 16 + l15;
      int pos = m * 4 + (quad ^ ((m >> 1) & 3));
      af[ms] = *(const bh8*)(a_lds + pos * 8);
    }
#pragma unroll
    for (int ns = 0; ns < 4; ++ns) {
      int n = nw + ns * 16 + l15;
      int pos = n * 4 + (quad ^ ((n >> 1) & 3));
      bfr[ns] = *(const bh8*)(b_lds + pos * 8);
    }
#pragma unroll
    for (int ms = 0; ms < 4; ++ms)
#pragma unroll
      for (int ns = 0; ns < 4; ++ns)
        acc[ms][ns] = __builtin_amdgcn_mfma_f32_16x16x32_bf16(af[ms], bfr[ns], acc[ms][ns], 0, 0, 0);
    __syncthreads();
  }
#pragma unroll
  for (int ns = 0; ns < 4; ++ns) {
    int col = n0 + nw + ns * 16 + l15;
    float bcol = BROW ? 0.f : bias[col & 1023];
#pragma unroll
    for (int ms = 0; ms < 4; ++ms) {
      int row = m0 + mw + ms * 16 + quad * 4;
      float brow = BROW ? bias[row & 1023] : 0.f;
#pragma unroll
      for (int r = 0; r < 4; ++r) {
        float bv = BROW ? bias[(row + r) & 1023] : bcol;
        float v = (acc[ms][ns][r] + bv) * scale;
        if (sizeof(OutT) == 2)
          ((short*)C)[(size_t)(row + r) * N + col] = f2bf(v);
        else
          ((float*)C)[(size_t)(row + r) * N + col] = v;
      }
      (void)brow;
    }
  }
}

// fused Q/K/V^T projection: grid.x = 24 (which = bx>>3), grid.y = 64
// which 0: Q = x Wq^T (scaled log2e/8), which 1: K = x Wk^T, which 2: V^T = Wv x^T
__global__ void gemm_qkv(const short* __restrict__ xb, const short* __restrict__ W3,
                         const float* __restrict__ bq, const float* __restrict__ bk,
                         const float* __restrict__ bv,
                         short* __restrict__ Qo, short* __restrict__ Ko, short* __restrict__ VTo,
                         float qscale) {
  __shared__ __align__(16) short a_lds[128 * 32];
  __shared__ __align__(16) short b_lds[128 * 32];
  const int which = blockIdx.x >> 3;
  if (which == 2) {
    const short* Wv = W3 + (size_t)2 * 1024 * 1024;
    gemm_body<short, true>(Wv, xb, bv, VTo, (blockIdx.x & 7) * 128, blockIdx.y * 128,
                           8192, 1024, 1.0f, a_lds, b_lds);
  } else {
    const short* Bw = W3 + (size_t)which * 1024 * 1024;
    const float* bias = which == 0 ? bq : bk;
    short* C = which == 0 ? Qo : Ko;
    float scale = which == 0 ? qscale : 1.0f;
    gemm_body<short, false>(xb, Bw, bias, C, blockIdx.y * 128, (blockIdx.x & 7) * 128,
                            1024, 1024, scale, a_lds, b_lds);
  }
}

__global__ void gemm_bt_f32(const short* __restrict__ A, const short* __restrict__ Bw,
                            const float* __restrict__ bias, float* __restrict__ C) {
  __shared__ __align__(16) short a_lds[128 * 32];
  __shared__ __align__(16) short b_lds[128 * 32];
  gemm_body<float, false>(A, Bw, bias, C, blockIdx.y * 128, blockIdx.x * 128, 1024, 1024, 1.0f,
                          a_lds, b_lds);
}

// ---------------- Flash attention (S^T formulation, static softmax bound) ----------------
// Q pre-scaled by log2(e)/8 -> exp2 domain. Static bound MB=16 folded into MFMA C-init:
// p = exp2(S - 16); softmax normalization makes this exact (no overflow until S>139).
//
// v5: NO K/V LDS staging, NO barriers. r0-r4 established: dur is pinned at 91-97us across
// occupancy 19-69% and DS traffic 48-144 b128/tile -> the invariant wall is the
// stage->vmcnt(0)-drain->barrier serialization. K/V per head (256KB+256KB) is L2-resident
// and shared by 16 blocks (guide common-mistake #7: don't LDS-stage L2-fit data).
// Each wave now loads K/V^T fragments DIRECTLY global->VGPR (16x global_load_dwordx4
// per tile: 16 rows x 64B segments, L2-friendly); waves free-run with zero __syncthreads.
// Only LDS left: per-wave p_lds round-trip (same-wave DS ordering needs no barrier).
// Geometry unchanged from v4: 2 waves x 64 Q-rows, grid (16,64).
__global__ __launch_bounds__(128, 2) void attn_kernel(const short* __restrict__ Qb,
                                                      const short* __restrict__ Kb,
                                                      const short* __restrict__ VTb,
                                                      short* __restrict__ AO) {
  __shared__ __align__(16) short p_lds[2][16 * 72];  // per-wave P[q(16)][key], stride 72; mi time-shared
  const int t = threadIdx.x, lane = t & 63, wave = t >> 6, quad = lane >> 4, l15 = lane & 15;
  const int bh = blockIdx.y, b = bh >> 4, h = bh & 15;
  const int q0 = blockIdx.x * 128;
  const size_t baseq = ((size_t)b * 2048) * 1024 + (size_t)h * 64;
  const size_t basev = ((size_t)h * 64) * 8192 + (size_t)b * 2048;

  // Q fragments in registers (B-operand: n=l15 -> q, k=quad*8+j -> d); wave owns 64 rows
  bh8 qf[4][2];
#pragma unroll
  for (int mi = 0; mi < 4; ++mi)
#pragma unroll
    for (int ks = 0; ks < 2; ++ks)
      qf[mi][ks] = *(const bh8*)(Qb + baseq + (size_t)(q0 + wave * 64 + mi * 16 + l15) * 1024 + ks * 32 + quad * 8);

  f4 O[4][4];
  float l_part[4] = {0.f, 0.f, 0.f, 0.f};
#pragma unroll
  for (int mi = 0; mi < 4; ++mi)
#pragma unroll
    for (int di = 0; di < 4; ++di) O[mi][di] = (f4){0.f, 0.f, 0.f, 0.f};

  // per-lane invariant bases:
  // K fragment ka{0,1}[mK] = K[kt + mK*16 + l15][{0,32} + quad*8 ..+7]
  // V fragment vb{0,1}[di] = VT[di*16 + l15][kt + {0,32} + quad*8 ..+7]
  const short* kbase = Kb + baseq + (size_t)l15 * 1024 + quad * 8;
  const short* vbase = VTb + basev + (size_t)l15 * 8192 + quad * 8;

  for (int kt = 0; kt < 2048; kt += 64) {
    // issue all 16 fragment loads up front; MFMAs consume in order while later loads fly
    const short* kb_t = kbase + (size_t)kt * 1024;
    const short* vb_t = vbase + kt;
    bh8 ka0[4], ka1[4], vb0[4], vb1[4];
#pragma unroll
    for (int mK = 0; mK < 4; ++mK) {
      ka0[mK] = *(const bh8*)(kb_t + (size_t)mK * 16 * 1024);
      ka1[mK] = *(const bh8*)(kb_t + (size_t)mK * 16 * 1024 + 32);
    }
#pragma unroll
    for (int di = 0; di < 4; ++di) {
      vb0[di] = *(const bh8*)(vb_t + (size_t)di * 16 * 8192);
      vb1[di] = *(const bh8*)(vb_t + (size_t)di * 16 * 8192 + 32);
    }

    // per mi: S^T-16 MFMAs, exp2, pack, p_lds round-trip (16-row buffer time-shared)
    bh8 pa[4][2];
#pragma unroll
    for (int mi = 0; mi < 4; ++mi) {
      f4 ST[4];
#pragma unroll
      for (int mK = 0; mK < 4; ++mK) {
        f4 s = (f4){-16.f, -16.f, -16.f, -16.f};
        s = __builtin_amdgcn_mfma_f32_16x16x32_bf16(ka0[mK], qf[mi][0], s, 0, 0, 0);
        s = __builtin_amdgcn_mfma_f32_16x16x32_bf16(ka1[mK], qf[mi][1], s, 0, 0, 0);
        ST[mK] = s;
      }
      float lp = 0.f;
#pragma unroll
      for (int mK = 0; mK < 4; ++mK) {
        float p0 = EXP2(ST[mK][0]);
        float p1 = EXP2(ST[mK][1]);
        float p2 = EXP2(ST[mK][2]);
        float p3 = EXP2(ST[mK][3]);
        lp += (p0 + p1) + (p2 + p3);
        u32 d0 = __builtin_amdgcn_perm(__float_as_uint(p1), __float_as_uint(p0), 0x07060302u);
        u32 d1 = __builtin_amdgcn_perm(__float_as_uint(p3), __float_as_uint(p2), 0x07060302u);
        u32x2 dd = {d0, d1};
        *(u32x2*)(&p_lds[wave][l15 * 72 + mK * 16 + quad * 4]) = dd;
      }
      l_part[mi] += lp;
      // same-wave DS in-order: reads of this mi complete before next mi's overwrites
#pragma unroll
      for (int ks = 0; ks < 2; ++ks)
        pa[mi][ks] = *(const bh8*)(&p_lds[wave][l15 * 72 + ks * 32 + quad * 8]);
    }

    // O += P V : vb fragments serve all 4 mi
#pragma unroll
    for (int di = 0; di < 4; ++di) {
#pragma unroll
      for (int mi = 0; mi < 4; ++mi) {
        f4 o = O[mi][di];
        o = __builtin_amdgcn_mfma_f32_16x16x32_bf16(pa[mi][0], vb0[di], o, 0, 0, 0);
        o = __builtin_amdgcn_mfma_f32_16x16x32_bf16(pa[mi][1], vb1[di], o, 0, 0, 0);
        O[mi][di] = o;
      }
    }
  }

  // epilogue: reduce l across quads (lanes sharing l15), broadcast 1/l to O rows, store
#pragma unroll
  for (int mi = 0; mi < 4; ++mi) {
    float l0 = l_part[mi];
    l0 += __shfl_xor(l0, 16);
    l0 += __shfl_xor(l0, 32);
    float rl[4];
#pragma unroll
    for (int r = 0; r < 4; ++r) {
      float lb = __shfl(l0, quad * 4 + r);
      rl[r] = __builtin_amdgcn_rcpf(lb);
    }
#pragma unroll
    for (int di = 0; di < 4; ++di)
#pragma unroll
      for (int r = 0; r < 4; ++r) {
        int row = q0 + wave * 64 + mi * 16 + quad * 4 + r;
        AO[baseq + (size_t)row * 1024 + di * 16 + l15] = f2bf(O[mi][di][r] * rl[r]);
      }
  }
}

// ---------------- launch ----------------
extern "C" void kernel_launch(void* const* d_in, const int* in_sizes, int n_in,
                              void* d_out, int out_size, void* d_ws, size_t ws_size,
                              hipStream_t stream) {
  const float* x  = (const float*)d_in[0];
  const float* Wq = (const float*)d_in[1];
  const float* bq = (const float*)d_in[2];
  const float* Wk = (const float*)d_in[3];
  const float* bk = (const float*)d_in[4];
  const float* Wv = (const float*)d_in[5];
  const float* bv = (const float*)d_in[6];
  const float* Wo = (const float*)d_in[7];
  const float* bo = (const float*)d_in[8];
  float* out = (float*)d_out;

  const int M = 8192, E = 1024;
  const size_t NX = (size_t)M * E;
  const size_t NW = (size_t)E * E;

  short* ws  = (short*)d_ws;
  short* xb  = ws;            // x bf16 [M][E]
  short* wqb = xb + NX;       // weights contiguous: wq, wk, wv, wo
  short* wob = wqb + 3 * NW;
  short* qb  = wob + NW;      // Q bf16 (pre-scaled by log2e/8)
  short* kb  = qb + NX;
  short* vt  = kb + NX;       // V^T bf16 [E][M] (t-contiguous rows)
  short* aob = xb;            // attention output aliases xb (xb dead after QKV GEMM)

  cvt_kernel<<<dim3((unsigned)(NX / 1024)), 256, 0, stream>>>(x, xb, (int)(NX / 4));
  cvt_w4<<<dim3((unsigned)(NW / 1024), 4), 256, 0, stream>>>(Wq, Wk, Wv, Wo, wqb, (int)(NW / 4));

  const float qscale = 0.18033688011112042f;  // log2(e) / sqrt(64)
  gemm_qkv<<<dim3(24, 64), 256, 0, stream>>>(xb, wqb, bq, bk, bv, qb, kb, vt, qscale);

  attn_kernel<<<dim3(16, 64), 128, 0, stream>>>(qb, kb, vt, aob);

  gemm_bt_f32<<<dim3(8, 64), 256, 0, stream>>>(aob, wob, bo, out);
}

// Round 6
// 276.745 us; speedup vs baseline: 1.1433x; 1.1433x over previous
//
#include <hip/hip_runtime.h>

typedef short bh8 __attribute__((ext_vector_type(8)));
typedef short bh4 __attribute__((ext_vector_type(4)));
typedef float f4 __attribute__((ext_vector_type(4)));
typedef unsigned int u32;
typedef u32 u32x2 __attribute__((ext_vector_type(2)));

#if __has_builtin(__builtin_amdgcn_exp2f)
#define EXP2(x) __builtin_amdgcn_exp2f(x)
#else
#define EXP2(x) exp2f(x)
#endif

__device__ __forceinline__ short f2bf(float f) {
  unsigned u = __float_as_uint(f);
  u += 0x7FFFu + ((u >> 16) & 1u);
  return (short)(u >> 16);
}

__device__ __forceinline__ void async16(const void* g, void* l) {
  __builtin_amdgcn_global_load_lds((const __attribute__((address_space(1))) void*)g,
                                   (__attribute__((address_space(3))) void*)l, 16, 0, 0);
}

// ---------------- fp32 -> bf16 convert (x) ----------------
__global__ void cvt_kernel(const float* __restrict__ in, short* __restrict__ out, int n4) {
  int i = blockIdx.x * blockDim.x + threadIdx.x;
  if (i < n4) {
    f4 v = *(const f4*)(in + (size_t)i * 4);
    bh4 o;
    o[0] = f2bf(v[0]); o[1] = f2bf(v[1]); o[2] = f2bf(v[2]); o[3] = f2bf(v[3]);
    *(bh4*)(out + (size_t)i * 4) = o;
  }
}

// ---------------- fused weight converts (Wq,Wk,Wv,Wo -> contiguous bf16) ----------------
__global__ void cvt_w4(const float* __restrict__ w0, const float* __restrict__ w1,
                       const float* __restrict__ w2, const float* __restrict__ w3,
                       short* __restrict__ out, int n4_per) {
  const float* in = blockIdx.y == 0 ? w0 : blockIdx.y == 1 ? w1 : blockIdx.y == 2 ? w2 : w3;
  short* o = out + (size_t)blockIdx.y * (size_t)n4_per * 4;
  int i = blockIdx.x * blockDim.x + threadIdx.x;
  if (i < n4_per) {
    f4 v = *(const f4*)(in + (size_t)i * 4);
    bh4 q;
    q[0] = f2bf(v[0]); q[1] = f2bf(v[1]); q[2] = f2bf(v[2]); q[3] = f2bf(v[3]);
    *(bh4*)(o + (size_t)i * 4) = q;
  }
}

// ---------------- GEMM core (128x128 tile, BK=32, 4 waves, 2-phase dbuf) ----------------
// v6: T3-minimum 2-phase pipeline (m230 recipe). r0-r5 budget analysis: gemm_bt runs at
// ~200 TF because its grid (512 blocks) gives only 2 blocks/CU -- no cross-block TLP to
// cover the per-K-step vmcnt(0) drain of the old sync;stage;sync;compute loop. Double-
// buffered LDS + {STAGE(next) -> compute(cur) -> vmcnt(0)+barrier} hides stage latency
// under compute WITHIN the block, removing the residency dependence. One barrier/K-step.
// C[m][n] = (sum_k A[m][k]*Bw[n][k] + bias) * scale; BROW: bias indexed by row (for V^T).
template <typename OutT, bool BROW>
__device__ __forceinline__ void gemm_body(const short* __restrict__ A, const short* __restrict__ Bw,
                                          const float* __restrict__ bias, OutT* __restrict__ C,
                                          int m0, int n0, int N, int K, float scale,
                                          short* a_lds, short* b_lds) {
  const int t = threadIdx.x;
  const int lane = t & 63, wave = t >> 6, quad = lane >> 4, l15 = lane & 15;
  const int mw = (wave >> 1) * 64, nw = (wave & 1) * 64;

  f4 acc[4][4];
#pragma unroll
  for (int i = 0; i < 4; ++i)
#pragma unroll
    for (int j = 0; j < 4; ++j) acc[i][j] = (f4){0.f, 0.f, 0.f, 0.f};

  // stage K-step k0 into buffer buf (each buffer: 128x32 shorts = 8KB per array)
  auto stage = [&](int k0, int buf) {
#pragma unroll
    for (int i = 0; i < 2; ++i) {
      int c = i * 256 + t;
      int m = c >> 2;
      int kq = (c & 3) ^ ((m >> 1) & 3);
      const short* ga = A + (size_t)(m0 + m) * K + k0 + kq * 8;
      const short* gb = Bw + (size_t)(n0 + m) * K + k0 + kq * 8;
      async16(ga, (char*)(a_lds + buf * 4096) + (i * 256 + wave * 64) * 16);
      async16(gb, (char*)(b_lds + buf * 4096) + (i * 256 + wave * 64) * 16);
    }
  };

  // prologue: stage K-step 0, drain, barrier
  stage(0, 0);
  asm volatile("s_waitcnt vmcnt(0)" ::: "memory");
  __builtin_amdgcn_s_barrier();
  asm volatile("" ::: "memory");

  int cur = 0;
  for (int k0 = 0; k0 < K; k0 += 32) {
    // issue next K-step's loads first; latency hides under this step's ds_read+MFMA
    if (k0 + 32 < K) stage(k0 + 32, cur ^ 1);
    const short* al = a_lds + cur * 4096;
    const short* bl = b_lds + cur * 4096;
    bh8 af[4], bfr[4];
#pragma unroll
    for (int ms = 0; ms < 4; ++ms) {
      int m = mw + ms * 16 + l15;
      int pos = m * 4 + (quad ^ ((m >> 1) & 3));
      af[ms] = *(const bh8*)(al + pos * 8);
    }
#pragma unroll
    for (int ns = 0; ns < 4; ++ns) {
      int n = nw + ns * 16 + l15;
      int pos = n * 4 + (quad ^ ((n >> 1) & 3));
      bfr[ns] = *(const bh8*)(bl + pos * 8);
    }
    // ds_reads complete before the MFMAs that consume them (compiler lgkmcnt);
    // all MFMAs issue before s_barrier, so reads of buf[cur] are drained at the barrier.
    __builtin_amdgcn_s_setprio(1);
#pragma unroll
    for (int ms = 0; ms < 4; ++ms)
#pragma unroll
      for (int ns = 0; ns < 4; ++ns)
        acc[ms][ns] = __builtin_amdgcn_mfma_f32_16x16x32_bf16(af[ms], bfr[ns], acc[ms][ns], 0, 0, 0);
    __builtin_amdgcn_s_setprio(0);
    // one barrier per K-step: own stage loads landed (vmcnt) + all waves done reading cur
    asm volatile("s_waitcnt vmcnt(0)" ::: "memory");
    __builtin_amdgcn_s_barrier();
    asm volatile("" ::: "memory");
    cur ^= 1;
  }
#pragma unroll
  for (int ns = 0; ns < 4; ++ns) {
    int col = n0 + nw + ns * 16 + l15;
    float bcol = BROW ? 0.f : bias[col & 1023];
#pragma unroll
    for (int ms = 0; ms < 4; ++ms) {
      int row = m0 + mw + ms * 16 + quad * 4;
#pragma unroll
      for (int r = 0; r < 4; ++r) {
        float bv = BROW ? bias[(row + r) & 1023] : bcol;
        float v = (acc[ms][ns][r] + bv) * scale;
        if (sizeof(OutT) == 2)
          ((short*)C)[(size_t)(row + r) * N + col] = f2bf(v);
        else
          ((float*)C)[(size_t)(row + r) * N + col] = v;
      }
    }
  }
}

// fused Q/K/V^T projection: grid.x = 24 (which = bx>>3), grid.y = 64
// which 0: Q = x Wq^T (scaled log2e/8), which 1: K = x Wk^T, which 2: V^T = Wv x^T
__global__ void gemm_qkv(const short* __restrict__ xb, const short* __restrict__ W3,
                         const float* __restrict__ bq, const float* __restrict__ bk,
                         const float* __restrict__ bv,
                         short* __restrict__ Qo, short* __restrict__ Ko, short* __restrict__ VTo,
                         float qscale) {
  __shared__ __align__(16) short a_lds[2 * 128 * 32];
  __shared__ __align__(16) short b_lds[2 * 128 * 32];
  const int which = blockIdx.x >> 3;
  if (which == 2) {
    const short* Wv = W3 + (size_t)2 * 1024 * 1024;
    gemm_body<short, true>(Wv, xb, bv, VTo, (blockIdx.x & 7) * 128, blockIdx.y * 128,
                           8192, 1024, 1.0f, a_lds, b_lds);
  } else {
    const short* Bw = W3 + (size_t)which * 1024 * 1024;
    const float* bias = which == 0 ? bq : bk;
    short* C = which == 0 ? Qo : Ko;
    float scale = which == 0 ? qscale : 1.0f;
    gemm_body<short, false>(xb, Bw, bias, C, blockIdx.y * 128, (blockIdx.x & 7) * 128,
                            1024, 1024, scale, a_lds, b_lds);
  }
}

__global__ void gemm_bt_f32(const short* __restrict__ A, const short* __restrict__ Bw,
                            const float* __restrict__ bias, float* __restrict__ C) {
  __shared__ __align__(16) short a_lds[2 * 128 * 32];
  __shared__ __align__(16) short b_lds[2 * 128 * 32];
  gemm_body<float, false>(A, Bw, bias, C, blockIdx.y * 128, blockIdx.x * 128, 1024, 1024, 1.0f,
                          a_lds, b_lds);
}

// ---------------- Flash attention (S^T formulation, static softmax bound) ----------------
// Q pre-scaled by log2(e)/8 -> exp2 domain. Static bound MB=16 folded into MFMA C-init:
// p = exp2(S - 16); softmax normalization makes this exact (no overflow until S>139).
// l accumulated as per-lane partials; reduced once in epilogue. No per-iter max/alpha/rescale.
// grid: (T/128, B*H). 4 waves; wave owns 32 Q-rows. K-tiles of 64.
//
// v6 = v2 exactly (91.1us plateau). r0-r5 swept occupancy 19-69%, DS traffic 48-144
// b128/tile, dbuf, and de-staged variants: all 91-136us, v2/v0 structure best. Accepted.
__global__ void attn_kernel(const short* __restrict__ Qb, const short* __restrict__ Kb,
                            const short* __restrict__ VTb, short* __restrict__ AO) {
  __shared__ __align__(16) short k_lds[64 * 64];     // K tile, xor-chunk swizzled [key][d]
  __shared__ __align__(16) short vt_lds[64 * 64];    // V^T tile, xor-chunk swizzled [d][key]
  __shared__ __align__(16) short p_lds[4][16 * 72];  // per-wave P[q(16)][key], stride 72; mi time-shared
  const int t = threadIdx.x, lane = t & 63, wave = t >> 6, quad = lane >> 4, l15 = lane & 15;
  const int bh = blockIdx.y, b = bh >> 4, h = bh & 15;
  const int q0 = blockIdx.x * 128;
  const size_t baseq = ((size_t)b * 2048) * 1024 + (size_t)h * 64;
  const size_t basev = ((size_t)h * 64) * 8192 + (size_t)b * 2048;

  // Q fragments in registers (B-operand: n=l15 -> q, k=quad*8+j -> d)
  bh8 qf[2][2];
#pragma unroll
  for (int mi = 0; mi < 2; ++mi)
#pragma unroll
    for (int ks = 0; ks < 2; ++ks)
      qf[mi][ks] = *(const bh8*)(Qb + baseq + (size_t)(q0 + wave * 32 + mi * 16 + l15) * 1024 + ks * 32 + quad * 8);

  f4 O[2][4];
  float l_part[2] = {0.f, 0.f};
#pragma unroll
  for (int mi = 0; mi < 2; ++mi)
#pragma unroll
    for (int di = 0; di < 4; ++di) O[mi][di] = (f4){0.f, 0.f, 0.f, 0.f};

  for (int kt = 0; kt < 2048; kt += 64) {
    __syncthreads();  // prior tile's LDS reads done
    // stage K tile: chunk c -> (kk=c>>3, dq=(c&7)^(kk&7))
#pragma unroll
    for (int i = 0; i < 2; ++i) {
      int c = i * 256 + t;
      int kk = c >> 3;
      int dq = (c & 7) ^ (kk & 7);
      async16(Kb + baseq + (size_t)(kt + kk) * 1024 + dq * 8,
              (char*)k_lds + (i * 256 + wave * 64) * 16);
    }
    // stage V^T tile: chunk c -> (d=c>>3, kc=(c&7)^(d&7)); rows of VT are t-contiguous
#pragma unroll
    for (int i = 0; i < 2; ++i) {
      int c = i * 256 + t;
      int d = c >> 3;
      int kc = (c & 7) ^ (d & 7);
      async16(VTb + basev + (size_t)d * 8192 + kt + kc * 8,
              (char*)vt_lds + (i * 256 + wave * 64) * 16);
    }
    __syncthreads();  // staging complete (drains vmcnt)

    // S^T - 16 = K Q^T - 16 (C-init carries the static bound)
    f4 ST[4][2];
#pragma unroll
    for (int mK = 0; mK < 4; ++mK) {
      int key = mK * 16 + l15;
      bh8 ka0 = *(const bh8*)(k_lds + (key * 8 + (quad ^ (key & 7))) * 8);
      bh8 ka1 = *(const bh8*)(k_lds + (key * 8 + ((quad + 4) ^ (key & 7))) * 8);
#pragma unroll
      for (int mi = 0; mi < 2; ++mi) {
        f4 s = (f4){-16.f, -16.f, -16.f, -16.f};
        s = __builtin_amdgcn_mfma_f32_16x16x32_bf16(ka0, qf[mi][0], s, 0, 0, 0);
        s = __builtin_amdgcn_mfma_f32_16x16x32_bf16(ka1, qf[mi][1], s, 0, 0, 0);
        ST[mK][mi] = s;
      }
    }

    // p = exp2(ST), accumulate per-lane l partials, pack to bf16, LDS round-trip.
    // mi halves time-share the 16-row p_lds buffer: write(mi) then read pa[mi];
    // the mi=1 writes are ordered after the mi=0 reads by the in-order DS pipe.
    bh8 pa[2][2];
#pragma unroll
    for (int mi = 0; mi < 2; ++mi) {
      float lp = 0.f;
#pragma unroll
      for (int mK = 0; mK < 4; ++mK) {
        float p0 = EXP2(ST[mK][mi][0]);
        float p1 = EXP2(ST[mK][mi][1]);
        float p2 = EXP2(ST[mK][mi][2]);
        float p3 = EXP2(ST[mK][mi][3]);
        lp += (p0 + p1) + (p2 + p3);
        u32 d0 = __builtin_amdgcn_perm(__float_as_uint(p1), __float_as_uint(p0), 0x07060302u);
        u32 d1 = __builtin_amdgcn_perm(__float_as_uint(p3), __float_as_uint(p2), 0x07060302u);
        u32x2 dd = {d0, d1};
        *(u32x2*)(&p_lds[wave][l15 * 72 + mK * 16 + quad * 4]) = dd;
      }
      l_part[mi] += lp;
#pragma unroll
      for (int ks = 0; ks < 2; ++ks)
        pa[mi][ks] = *(const bh8*)(&p_lds[wave][l15 * 72 + ks * 32 + quad * 8]);
    }

    // O += P V
#pragma unroll
    for (int di = 0; di < 4; ++di) {
      int d = di * 16 + l15;
      bh8 vb0 = *(const bh8*)(vt_lds + (d * 8 + (quad ^ (d & 7))) * 8);
      bh8 vb1 = *(const bh8*)(vt_lds + (d * 8 + ((quad + 4) ^ (d & 7))) * 8);
#pragma unroll
      for (int mi = 0; mi < 2; ++mi) {
        f4 o = O[mi][di];
        o = __builtin_amdgcn_mfma_f32_16x16x32_bf16(pa[mi][0], vb0, o, 0, 0, 0);
        o = __builtin_amdgcn_mfma_f32_16x16x32_bf16(pa[mi][1], vb1, o, 0, 0, 0);
        O[mi][di] = o;
      }
    }
  }

  // epilogue: reduce l across quads (lanes sharing l15), broadcast 1/l to O rows, store
#pragma unroll
  for (int mi = 0; mi < 2; ++mi) {
    float l0 = l_part[mi];
    l0 += __shfl_xor(l0, 16);
    l0 += __shfl_xor(l0, 32);
    float rl[4];
#pragma unroll
    for (int r = 0; r < 4; ++r) {
      float lb = __shfl(l0, quad * 4 + r);
      rl[r] = __builtin_amdgcn_rcpf(lb);
    }
#pragma unroll
    for (int di = 0; di < 4; ++di)
#pragma unroll
      for (int r = 0; r < 4; ++r) {
        int row = q0 + wave * 32 + mi * 16 + quad * 4 + r;
        AO[baseq + (size_t)row * 1024 + di * 16 + l15] = f2bf(O[mi][di][r] * rl[r]);
      }
  }
}

// ---------------- launch ----------------
extern "C" void kernel_launch(void* const* d_in, const int* in_sizes, int n_in,
                              void* d_out, int out_size, void* d_ws, size_t ws_size,
                              hipStream_t stream) {
  const float* x  = (const float*)d_in[0];
  const float* Wq = (const float*)d_in[1];
  const float* bq = (const float*)d_in[2];
  const float* Wk = (const float*)d_in[3];
  const float* bk = (const float*)d_in[4];
  const float* Wv = (const float*)d_in[5];
  const float* bv = (const float*)d_in[6];
  const float* Wo = (const float*)d_in[7];
  const float* bo = (const float*)d_in[8];
  float* out = (float*)d_out;

  const int M = 8192, E = 1024;
  const size_t NX = (size_t)M * E;
  const size_t NW = (size_t)E * E;

  short* ws  = (short*)d_ws;
  short* xb  = ws;            // x bf16 [M][E]
  short* wqb = xb + NX;       // weights contiguous: wq, wk, wv, wo
  short* wob = wqb + 3 * NW;
  short* qb  = wob + NW;      // Q bf16 (pre-scaled by log2e/8)
  short* kb  = qb + NX;
  short* vt  = kb + NX;       // V^T bf16 [E][M] (t-contiguous rows)
  short* aob = xb;            // attention output aliases xb (xb dead after QKV GEMM)

  cvt_kernel<<<dim3((unsigned)(NX / 1024)), 256, 0, stream>>>(x, xb, (int)(NX / 4));
  cvt_w4<<<dim3((unsigned)(NW / 1024), 4), 256, 0, stream>>>(Wq, Wk, Wv, Wo, wqb, (int)(NW / 4));

  const float qscale = 0.18033688011112042f;  // log2(e) / sqrt(64)
  gemm_qkv<<<dim3(24, 64), 256, 0, stream>>>(xb, wqb, bq, bk, bv, qb, kb, vt, qscale);

  attn_kernel<<<dim3(16, 64), 256, 0, stream>>>(qb, kb, vt, aob);

  gemm_bt_f32<<<dim3(8, 64), 256, 0, stream>>>(aob, wob, bo, out);
}

// Round 7
// 261.101 us; speedup vs baseline: 1.2118x; 1.0599x over previous
//
#include <hip/hip_runtime.h>

typedef short bh8 __attribute__((ext_vector_type(8)));
typedef short bh4 __attribute__((ext_vector_type(4)));
typedef float f4 __attribute__((ext_vector_type(4)));
typedef unsigned int u32;
typedef u32 u32x2 __attribute__((ext_vector_type(2)));

#if __has_builtin(__builtin_amdgcn_exp2f)
#define EXP2(x) __builtin_amdgcn_exp2f(x)
#else
#define EXP2(x) exp2f(x)
#endif

__device__ __forceinline__ short f2bf(float f) {
  unsigned u = __float_as_uint(f);
  u += 0x7FFFu + ((u >> 16) & 1u);
  return (short)(u >> 16);
}

__device__ __forceinline__ void async16(const void* g, void* l) {
  __builtin_amdgcn_global_load_lds((const __attribute__((address_space(1))) void*)g,
                                   (__attribute__((address_space(3))) void*)l, 16, 0, 0);
}

// ---------------- fused fp32 -> bf16 convert: x + Wq,Wk,Wv,Wo in ONE launch ----------------
// n4 totals: x = 1<<21 f4-groups, each weight = 1<<18. Grid covers exactly (1<<21)+(4<<18).
__global__ void cvt_all(const float* __restrict__ x, const float* __restrict__ Wq,
                        const float* __restrict__ Wk, const float* __restrict__ Wv,
                        const float* __restrict__ Wo, short* __restrict__ xb,
                        short* __restrict__ wqb) {
  int i = blockIdx.x * blockDim.x + threadIdx.x;
  const float* src;
  short* dst;
  int idx;
  if (i < (1 << 21)) {
    src = x; dst = xb; idx = i;
  } else {
    int j = i - (1 << 21);
    int w = j >> 18;
    idx = j & ((1 << 18) - 1);
    src = w == 0 ? Wq : w == 1 ? Wk : w == 2 ? Wv : Wo;
    dst = wqb + ((size_t)w << 20);
  }
  f4 v = *(const f4*)(src + (size_t)idx * 4);
  bh4 o;
  o[0] = f2bf(v[0]); o[1] = f2bf(v[1]); o[2] = f2bf(v[2]); o[3] = f2bf(v[3]);
  *(bh4*)(dst + (size_t)idx * 4) = o;
}

// ---------------- GEMM core (128x128 tile, BK=64, 4 waves, single-buffer 2-barrier) -------
// v7: BK=32 -> 64. r6 showed 2-phase dbuf neutral (catalog-consistent): the per-step
// vmcnt(0) drain exposes (latency - compute) every K-step regardless. BK=64 halves the
// number of drain events (16 steps vs 32) and doubles per-step compute (16 ds_read +
// 32 MFMA ~ 700cyc >= stage latency), so the exposed stall fraction ~halves.
// LDS 32KB single-buffer; fragments loaded per k-slice to keep VGPR ~120 (4 waves/SIMD).
// Chunk swizzle: LDS[m][j] holds source k-chunk j^(m&7) (8 chunks/row); reader at
// chunk (s*4+quad) uses j=(s*4+quad)^(m&7) -- same involution both sides.
// C[m][n] = (sum_k A[m][k]*Bw[n][k] + bias) * scale; BROW: bias indexed by row (for V^T).
template <typename OutT, bool BROW>
__device__ __forceinline__ void gemm_body(const short* __restrict__ A, const short* __restrict__ Bw,
                                          const float* __restrict__ bias, OutT* __restrict__ C,
                                          int m0, int n0, int N, int K, float scale,
                                          short* a_lds, short* b_lds) {
  const int t = threadIdx.x;
  const int lane = t & 63, wave = t >> 6, quad = lane >> 4, l15 = lane & 15;
  const int mw = (wave >> 1) * 64, nw = (wave & 1) * 64;

  f4 acc[4][4];
#pragma unroll
  for (int i = 0; i < 4; ++i)
#pragma unroll
    for (int j = 0; j < 4; ++j) acc[i][j] = (f4){0.f, 0.f, 0.f, 0.f};

  for (int k0 = 0; k0 < K; k0 += 64) {
    __syncthreads();  // prior step's LDS reads done
    // stage A tile [128][64]: chunk c -> (m=c>>3, kq=(c&7)^(m&7)); LDS dest linear c*16
#pragma unroll
    for (int i = 0; i < 4; ++i) {
      int c = i * 256 + t;
      int m = c >> 3;
      int kq = (c & 7) ^ (m & 7);
      async16(A + (size_t)(m0 + m) * K + k0 + kq * 8, (char*)a_lds + c * 16);
    }
#pragma unroll
    for (int i = 0; i < 4; ++i) {
      int c = i * 256 + t;
      int m = c >> 3;
      int kq = (c & 7) ^ (m & 7);
      async16(Bw + (size_t)(n0 + m) * K + k0 + kq * 8, (char*)b_lds + c * 16);
    }
    __syncthreads();  // staging complete (drains vmcnt)

#pragma unroll
    for (int s = 0; s < 2; ++s) {
      bh8 af[4], bfr[4];
#pragma unroll
      for (int ms = 0; ms < 4; ++ms) {
        int m = mw + ms * 16 + l15;
        int pos = m * 8 + ((s * 4 + quad) ^ (m & 7));
        af[ms] = *(const bh8*)(a_lds + pos * 8);
      }
#pragma unroll
      for (int ns = 0; ns < 4; ++ns) {
        int n = nw + ns * 16 + l15;
        int pos = n * 8 + ((s * 4 + quad) ^ (n & 7));
        bfr[ns] = *(const bh8*)(b_lds + pos * 8);
      }
#pragma unroll
      for (int ms = 0; ms < 4; ++ms)
#pragma unroll
        for (int ns = 0; ns < 4; ++ns)
          acc[ms][ns] = __builtin_amdgcn_mfma_f32_16x16x32_bf16(af[ms], bfr[ns], acc[ms][ns], 0, 0, 0);
    }
  }
#pragma unroll
  for (int ns = 0; ns < 4; ++ns) {
    int col = n0 + nw + ns * 16 + l15;
    float bcol = BROW ? 0.f : bias[col & 1023];
#pragma unroll
    for (int ms = 0; ms < 4; ++ms) {
      int row = m0 + mw + ms * 16 + quad * 4;
#pragma unroll
      for (int r = 0; r < 4; ++r) {
        float bv = BROW ? bias[(row + r) & 1023] : bcol;
        float v = (acc[ms][ns][r] + bv) * scale;
        if (sizeof(OutT) == 2)
          ((short*)C)[(size_t)(row + r) * N + col] = f2bf(v);
        else
          ((float*)C)[(size_t)(row + r) * N + col] = v;
      }
    }
  }
}

// fused Q/K/V^T projection: grid.x = 24 (which = bx>>3), grid.y = 64
// which 0: Q = x Wq^T (scaled log2e/8), which 1: K = x Wk^T, which 2: V^T = Wv x^T
__global__ void gemm_qkv(const short* __restrict__ xb, const short* __restrict__ W3,
                         const float* __restrict__ bq, const float* __restrict__ bk,
                         const float* __restrict__ bv,
                         short* __restrict__ Qo, short* __restrict__ Ko, short* __restrict__ VTo,
                         float qscale) {
  __shared__ __align__(16) short a_lds[128 * 64];
  __shared__ __align__(16) short b_lds[128 * 64];
  const int which = blockIdx.x >> 3;
  if (which == 2) {
    const short* Wv = W3 + (size_t)2 * 1024 * 1024;
    gemm_body<short, true>(Wv, xb, bv, VTo, (blockIdx.x & 7) * 128, blockIdx.y * 128,
                           8192, 1024, 1.0f, a_lds, b_lds);
  } else {
    const short* Bw = W3 + (size_t)which * 1024 * 1024;
    const float* bias = which == 0 ? bq : bk;
    short* C = which == 0 ? Qo : Ko;
    float scale = which == 0 ? qscale : 1.0f;
    gemm_body<short, false>(xb, Bw, bias, C, blockIdx.y * 128, (blockIdx.x & 7) * 128,
                            1024, 1024, scale, a_lds, b_lds);
  }
}

__global__ void gemm_bt_f32(const short* __restrict__ A, const short* __restrict__ Bw,
                            const float* __restrict__ bias, float* __restrict__ C) {
  __shared__ __align__(16) short a_lds[128 * 64];
  __shared__ __align__(16) short b_lds[128 * 64];
  gemm_body<float, false>(A, Bw, bias, C, blockIdx.y * 128, blockIdx.x * 128, 1024, 1024, 1.0f,
                          a_lds, b_lds);
}

// ---------------- Flash attention (S^T formulation, static softmax bound) ----------------
// Q pre-scaled by log2(e)/8 -> exp2 domain. Static bound MB=16 folded into MFMA C-init:
// p = exp2(S - 16); softmax normalization makes this exact (no overflow until S>139).
// l accumulated as per-lane partials; reduced once in epilogue. No per-iter max/alpha/rescale.
// grid: (T/128, B*H). 4 waves; wave owns 32 Q-rows. K-tiles of 64.
// v7 = v2/v6 structure (accepted 90us plateau; r0-r5 swept occupancy/DS-traffic/dbuf).
__global__ void attn_kernel(const short* __restrict__ Qb, const short* __restrict__ Kb,
                            const short* __restrict__ VTb, short* __restrict__ AO) {
  __shared__ __align__(16) short k_lds[64 * 64];     // K tile, xor-chunk swizzled [key][d]
  __shared__ __align__(16) short vt_lds[64 * 64];    // V^T tile, xor-chunk swizzled [d][key]
  __shared__ __align__(16) short p_lds[4][16 * 72];  // per-wave P[q(16)][key], stride 72; mi time-shared
  const int t = threadIdx.x, lane = t & 63, wave = t >> 6, quad = lane >> 4, l15 = lane & 15;
  const int bh = blockIdx.y, b = bh >> 4, h = bh & 15;
  const int q0 = blockIdx.x * 128;
  const size_t baseq = ((size_t)b * 2048) * 1024 + (size_t)h * 64;
  const size_t basev = ((size_t)h * 64) * 8192 + (size_t)b * 2048;

  // Q fragments in registers (B-operand: n=l15 -> q, k=quad*8+j -> d)
  bh8 qf[2][2];
#pragma unroll
  for (int mi = 0; mi < 2; ++mi)
#pragma unroll
    for (int ks = 0; ks < 2; ++ks)
      qf[mi][ks] = *(const bh8*)(Qb + baseq + (size_t)(q0 + wave * 32 + mi * 16 + l15) * 1024 + ks * 32 + quad * 8);

  f4 O[2][4];
  float l_part[2] = {0.f, 0.f};
#pragma unroll
  for (int mi = 0; mi < 2; ++mi)
#pragma unroll
    for (int di = 0; di < 4; ++di) O[mi][di] = (f4){0.f, 0.f, 0.f, 0.f};

  for (int kt = 0; kt < 2048; kt += 64) {
    __syncthreads();  // prior tile's LDS reads done
    // stage K tile: chunk c -> (kk=c>>3, dq=(c&7)^(kk&7))
#pragma unroll
    for (int i = 0; i < 2; ++i) {
      int c = i * 256 + t;
      int kk = c >> 3;
      int dq = (c & 7) ^ (kk & 7);
      async16(Kb + baseq + (size_t)(kt + kk) * 1024 + dq * 8,
              (char*)k_lds + (i * 256 + wave * 64) * 16);
    }
    // stage V^T tile: chunk c -> (d=c>>3, kc=(c&7)^(d&7)); rows of VT are t-contiguous
#pragma unroll
    for (int i = 0; i < 2; ++i) {
      int c = i * 256 + t;
      int d = c >> 3;
      int kc = (c & 7) ^ (d & 7);
      async16(VTb + basev + (size_t)d * 8192 + kt + kc * 8,
              (char*)vt_lds + (i * 256 + wave * 64) * 16);
    }
    __syncthreads();  // staging complete (drains vmcnt)

    // S^T - 16 = K Q^T - 16 (C-init carries the static bound)
    f4 ST[4][2];
#pragma unroll
    for (int mK = 0; mK < 4; ++mK) {
      int key = mK * 16 + l15;
      bh8 ka0 = *(const bh8*)(k_lds + (key * 8 + (quad ^ (key & 7))) * 8);
      bh8 ka1 = *(const bh8*)(k_lds + (key * 8 + ((quad + 4) ^ (key & 7))) * 8);
#pragma unroll
      for (int mi = 0; mi < 2; ++mi) {
        f4 s = (f4){-16.f, -16.f, -16.f, -16.f};
        s = __builtin_amdgcn_mfma_f32_16x16x32_bf16(ka0, qf[mi][0], s, 0, 0, 0);
        s = __builtin_amdgcn_mfma_f32_16x16x32_bf16(ka1, qf[mi][1], s, 0, 0, 0);
        ST[mK][mi] = s;
      }
    }

    // p = exp2(ST), accumulate per-lane l partials, pack to bf16, LDS round-trip.
    // mi halves time-share the 16-row p_lds buffer (same-wave DS ops are in-order).
    bh8 pa[2][2];
#pragma unroll
    for (int mi = 0; mi < 2; ++mi) {
      float lp = 0.f;
#pragma unroll
      for (int mK = 0; mK < 4; ++mK) {
        float p0 = EXP2(ST[mK][mi][0]);
        float p1 = EXP2(ST[mK][mi][1]);
        float p2 = EXP2(ST[mK][mi][2]);
        float p3 = EXP2(ST[mK][mi][3]);
        lp += (p0 + p1) + (p2 + p3);
        u32 d0 = __builtin_amdgcn_perm(__float_as_uint(p1), __float_as_uint(p0), 0x07060302u);
        u32 d1 = __builtin_amdgcn_perm(__float_as_uint(p3), __float_as_uint(p2), 0x07060302u);
        u32x2 dd = {d0, d1};
        *(u32x2*)(&p_lds[wave][l15 * 72 + mK * 16 + quad * 4]) = dd;
      }
      l_part[mi] += lp;
#pragma unroll
      for (int ks = 0; ks < 2; ++ks)
        pa[mi][ks] = *(const bh8*)(&p_lds[wave][l15 * 72 + ks * 32 + quad * 8]);
    }

    // O += P V
#pragma unroll
    for (int di = 0; di < 4; ++di) {
      int d = di * 16 + l15;
      bh8 vb0 = *(const bh8*)(vt_lds + (d * 8 + (quad ^ (d & 7))) * 8);
      bh8 vb1 = *(const bh8*)(vt_lds + (d * 8 + ((quad + 4) ^ (d & 7))) * 8);
#pragma unroll
      for (int mi = 0; mi < 2; ++mi) {
        f4 o = O[mi][di];
        o = __builtin_amdgcn_mfma_f32_16x16x32_bf16(pa[mi][0], vb0, o, 0, 0, 0);
        o = __builtin_amdgcn_mfma_f32_16x16x32_bf16(pa[mi][1], vb1, o, 0, 0, 0);
        O[mi][di] = o;
      }
    }
  }

  // epilogue: reduce l across quads (lanes sharing l15), broadcast 1/l to O rows, store
#pragma unroll
  for (int mi = 0; mi < 2; ++mi) {
    float l0 = l_part[mi];
    l0 += __shfl_xor(l0, 16);
    l0 += __shfl_xor(l0, 32);
    float rl[4];
#pragma unroll
    for (int r = 0; r < 4; ++r) {
      float lb = __shfl(l0, quad * 4 + r);
      rl[r] = __builtin_amdgcn_rcpf(lb);
    }
#pragma unroll
    for (int di = 0; di < 4; ++di)
#pragma unroll
      for (int r = 0; r < 4; ++r) {
        int row = q0 + wave * 32 + mi * 16 + quad * 4 + r;
        AO[baseq + (size_t)row * 1024 + di * 16 + l15] = f2bf(O[mi][di][r] * rl[r]);
      }
  }
}

// ---------------- launch ----------------
extern "C" void kernel_launch(void* const* d_in, const int* in_sizes, int n_in,
                              void* d_out, int out_size, void* d_ws, size_t ws_size,
                              hipStream_t stream) {
  const float* x  = (const float*)d_in[0];
  const float* Wq = (const float*)d_in[1];
  const float* bq = (const float*)d_in[2];
  const float* Wk = (const float*)d_in[3];
  const float* bk = (const float*)d_in[4];
  const float* Wv = (const float*)d_in[5];
  const float* bv = (const float*)d_in[6];
  const float* Wo = (const float*)d_in[7];
  const float* bo = (const float*)d_in[8];
  float* out = (float*)d_out;

  const int M = 8192, E = 1024;
  const size_t NX = (size_t)M * E;
  const size_t NW = (size_t)E * E;

  short* ws  = (short*)d_ws;
  short* xb  = ws;            // x bf16 [M][E]
  short* wqb = xb + NX;       // weights contiguous: wq, wk, wv, wo
  short* wob = wqb + 3 * NW;
  short* qb  = wob + NW;      // Q bf16 (pre-scaled by log2e/8)
  short* kb  = qb + NX;
  short* vt  = kb + NX;       // V^T bf16 [E][M] (t-contiguous rows)
  short* aob = xb;            // attention output aliases xb (xb dead after QKV GEMM)

  // fused convert: (NX + 4*NW)/4 f4-groups / 256 threads = 12288 blocks exactly
  cvt_all<<<dim3(12288), 256, 0, stream>>>(x, Wq, Wk, Wv, Wo, xb, wqb);

  const float qscale = 0.18033688011112042f;  // log2(e) / sqrt(64)
  gemm_qkv<<<dim3(24, 64), 256, 0, stream>>>(xb, wqb, bq, bk, bv, qb, kb, vt, qscale);

  attn_kernel<<<dim3(16, 64), 256, 0, stream>>>(qb, kb, vt, aob);

  gemm_bt_f32<<<dim3(8, 64), 256, 0, stream>>>(aob, wob, bo, out);
}

// Round 8
// 261.058 us; speedup vs baseline: 1.2120x; 1.0002x over previous
//
#include <hip/hip_runtime.h>

typedef short bh8 __attribute__((ext_vector_type(8)));
typedef short bh4 __attribute__((ext_vector_type(4)));
typedef float f4 __attribute__((ext_vector_type(4)));
typedef unsigned int u32;
typedef u32 u32x2 __attribute__((ext_vector_type(2)));

#if __has_builtin(__builtin_amdgcn_exp2f)
#define EXP2(x) __builtin_amdgcn_exp2f(x)
#else
#define EXP2(x) exp2f(x)
#endif

__device__ __forceinline__ short f2bf(float f) {
  unsigned u = __float_as_uint(f);
  u += 0x7FFFu + ((u >> 16) & 1u);
  return (short)(u >> 16);
}

__device__ __forceinline__ void async16(const void* g, void* l) {
  __builtin_amdgcn_global_load_lds((const __attribute__((address_space(1))) void*)g,
                                   (__attribute__((address_space(3))) void*)l, 16, 0, 0);
}

// ---------------- fused fp32 -> bf16 convert: x + Wq,Wk,Wv,Wo in ONE launch ----------------
__global__ void cvt_all(const float* __restrict__ x, const float* __restrict__ Wq,
                        const float* __restrict__ Wk, const float* __restrict__ Wv,
                        const float* __restrict__ Wo, short* __restrict__ xb,
                        short* __restrict__ wqb) {
  int i = blockIdx.x * blockDim.x + threadIdx.x;
  const float* src;
  short* dst;
  int idx;
  if (i < (1 << 21)) {
    src = x; dst = xb; idx = i;
  } else {
    int j = i - (1 << 21);
    int w = j >> 18;
    idx = j & ((1 << 18) - 1);
    src = w == 0 ? Wq : w == 1 ? Wk : w == 2 ? Wv : Wo;
    dst = wqb + ((size_t)w << 20);
  }
  f4 v = *(const f4*)(src + (size_t)idx * 4);
  bh4 o;
  o[0] = f2bf(v[0]); o[1] = f2bf(v[1]); o[2] = f2bf(v[2]); o[3] = f2bf(v[3]);
  *(bh4*)(dst + (size_t)idx * 4) = o;
}

// ---------------- GEMM core (128x128 tile, BK=64, 4 waves, single-buffer 2-barrier) -------
// v7: BK=64 (16 K-steps; per-step compute ~>= stage latency -> fewer exposed drains). v8 adds
// XCD working-set clustering at the call sites (see kernels below).
// C[m][n] = (sum_k A[m][k]*Bw[n][k] + bias) * scale; BROW: bias indexed by row (for V^T).
template <typename OutT, bool BROW>
__device__ __forceinline__ void gemm_body(const short* __restrict__ A, const short* __restrict__ Bw,
                                          const float* __restrict__ bias, OutT* __restrict__ C,
                                          int m0, int n0, int N, int K, float scale,
                                          short* a_lds, short* b_lds) {
  const int t = threadIdx.x;
  const int lane = t & 63, wave = t >> 6, quad = lane >> 4, l15 = lane & 15;
  const int mw = (wave >> 1) * 64, nw = (wave & 1) * 64;

  f4 acc[4][4];
#pragma unroll
  for (int i = 0; i < 4; ++i)
#pragma unroll
    for (int j = 0; j < 4; ++j) acc[i][j] = (f4){0.f, 0.f, 0.f, 0.f};

  for (int k0 = 0; k0 < K; k0 += 64) {
    __syncthreads();  // prior step's LDS reads done
    // stage A tile [128][64]: chunk c -> (m=c>>3, kq=(c&7)^(m&7)); LDS dest linear c*16
#pragma unroll
    for (int i = 0; i < 4; ++i) {
      int c = i * 256 + t;
      int m = c >> 3;
      int kq = (c & 7) ^ (m & 7);
      async16(A + (size_t)(m0 + m) * K + k0 + kq * 8, (char*)a_lds + c * 16);
    }
#pragma unroll
    for (int i = 0; i < 4; ++i) {
      int c = i * 256 + t;
      int m = c >> 3;
      int kq = (c & 7) ^ (m & 7);
      async16(Bw + (size_t)(n0 + m) * K + k0 + kq * 8, (char*)b_lds + c * 16);
    }
    __syncthreads();  // staging complete (drains vmcnt)

#pragma unroll
    for (int s = 0; s < 2; ++s) {
      bh8 af[4], bfr[4];
#pragma unroll
      for (int ms = 0; ms < 4; ++ms) {
        int m = mw + ms * 16 + l15;
        int pos = m * 8 + ((s * 4 + quad) ^ (m & 7));
        af[ms] = *(const bh8*)(a_lds + pos * 8);
      }
#pragma unroll
      for (int ns = 0; ns < 4; ++ns) {
        int n = nw + ns * 16 + l15;
        int pos = n * 8 + ((s * 4 + quad) ^ (n & 7));
        bfr[ns] = *(const bh8*)(b_lds + pos * 8);
      }
#pragma unroll
      for (int ms = 0; ms < 4; ++ms)
#pragma unroll
        for (int ns = 0; ns < 4; ++ns)
          acc[ms][ns] = __builtin_amdgcn_mfma_f32_16x16x32_bf16(af[ms], bfr[ns], acc[ms][ns], 0, 0, 0);
    }
  }
#pragma unroll
  for (int ns = 0; ns < 4; ++ns) {
    int col = n0 + nw + ns * 16 + l15;
    float bcol = BROW ? 0.f : bias[col & 1023];
#pragma unroll
    for (int ms = 0; ms < 4; ++ms) {
      int row = m0 + mw + ms * 16 + quad * 4;
#pragma unroll
      for (int r = 0; r < 4; ++r) {
        float bv = BROW ? bias[(row + r) & 1023] : bcol;
        float v = (acc[ms][ns][r] + bv) * scale;
        if (sizeof(OutT) == 2)
          ((short*)C)[(size_t)(row + r) * N + col] = f2bf(v);
        else
          ((float*)C)[(size_t)(row + r) * N + col] = v;
      }
    }
  }
}

// fused Q/K/V^T projection: grid 24x64 = 1536 blocks.
// v8 XCD clustering: dispatch is x-fastest, XCD ~ linear%8. Remap so each XCD owns 8
// row-panels of x (2MB, L2-resident) across all (which,nx) combos; weights stream.
// Bijective: 1536 % 8 == 0.
__global__ void gemm_qkv(const short* __restrict__ xb, const short* __restrict__ W3,
                         const float* __restrict__ bq, const float* __restrict__ bk,
                         const float* __restrict__ bv,
                         short* __restrict__ Qo, short* __restrict__ Ko, short* __restrict__ VTo,
                         float qscale) {
  __shared__ __align__(16) short a_lds[128 * 64];
  __shared__ __align__(16) short b_lds[128 * 64];
  const int linear = blockIdx.y * 24 + blockIdx.x;
  const int xcd = linear & 7;
  const int slot = linear >> 3;          // 0..191
  const int byp = xcd * 8 + slot / 24;   // x row-panel cluster per XCD
  const int rest = slot % 24;
  const int which = rest >> 3;
  const int nx = rest & 7;
  if (which == 2) {
    const short* Wv = W3 + (size_t)2 * 1024 * 1024;
    gemm_body<short, true>(Wv, xb, bv, VTo, nx * 128, byp * 128,
                           8192, 1024, 1.0f, a_lds, b_lds);
  } else {
    const short* Bw = W3 + (size_t)which * 1024 * 1024;
    const float* bias = which == 0 ? bq : bk;
    short* C = which == 0 ? Qo : Ko;
    float scale = which == 0 ? qscale : 1.0f;
    gemm_body<short, false>(xb, Bw, bias, C, byp * 128, nx * 128,
                            1024, 1024, scale, a_lds, b_lds);
  }
}

// out-projection: grid 8x64 = 512 blocks. Pre-v8: linear%8 == bx, so each XCD touched ALL
// of A (16MB -> L2 thrash). Remap: each XCD owns 8 row-panels of A (2MB) + its Wo slice
// (2MB) -> whole working set L2-resident. Bijective: 512 % 8 == 0.
__global__ void gemm_bt_f32(const short* __restrict__ A, const short* __restrict__ Bw,
                            const float* __restrict__ bias, float* __restrict__ C) {
  __shared__ __align__(16) short a_lds[128 * 64];
  __shared__ __align__(16) short b_lds[128 * 64];
  const int linear = blockIdx.y * 8 + blockIdx.x;
  const int xcd = linear & 7;
  const int slot = linear >> 3;          // 0..63
  const int byp = xcd * 8 + (slot >> 3); // A row-panel cluster per XCD
  const int bxp = slot & 7;
  gemm_body<float, false>(A, Bw, bias, C, byp * 128, bxp * 128, 1024, 1024, 1.0f,
                          a_lds, b_lds);
}

// ---------------- Flash attention (S^T formulation, static softmax bound) ----------------
// Q pre-scaled by log2(e)/8 -> exp2 domain. Static bound MB=16 folded into MFMA C-init:
// p = exp2(S - 16); softmax normalization makes this exact (no overflow until S>139).
// l accumulated as per-lane partials; reduced once in epilogue.
// grid: (T/128, B*H) = (16,64) = 1024 blocks, all co-resident (4/CU).
//
// v8 XCD clustering: pre-v8 the 16 q-tile blocks of one head scattered across all 8 XCDs;
// each XCD's K/V working set was ~64 heads x 512KB >> 4MB L2 -> every tile-stage missed L2
// and paid L3/HBM latency inside the serial vmcnt-drain window (FETCH 139.7MB vs 48 ideal).
// Remap: XCD owns 8 whole heads (K/V = 4MB = exactly one L2); the 16 q-tiles of a head run
// near-lockstep on one XCD. Bijective: 1024 % 8 == 0.
__global__ void attn_kernel(const short* __restrict__ Qb, const short* __restrict__ Kb,
                            const short* __restrict__ VTb, short* __restrict__ AO) {
  __shared__ __align__(16) short k_lds[64 * 64];     // K tile, xor-chunk swizzled [key][d]
  __shared__ __align__(16) short vt_lds[64 * 64];    // V^T tile, xor-chunk swizzled [d][key]
  __shared__ __align__(16) short p_lds[4][16 * 72];  // per-wave P[q(16)][key], stride 72; mi time-shared
  const int t = threadIdx.x, lane = t & 63, wave = t >> 6, quad = lane >> 4, l15 = lane & 15;
  const int linear = blockIdx.y * 16 + blockIdx.x;
  const int xcd = linear & 7;
  const int slot = linear >> 3;            // 0..127
  const int bh = xcd * 8 + (slot >> 4);    // head cluster: 8 heads per XCD
  const int qx = slot & 15;
  const int b = bh >> 4, h = bh & 15;
  const int q0 = qx * 128;
  const size_t baseq = ((size_t)b * 2048) * 1024 + (size_t)h * 64;
  const size_t basev = ((size_t)h * 64) * 8192 + (size_t)b * 2048;

  // Q fragments in registers (B-operand: n=l15 -> q, k=quad*8+j -> d)
  bh8 qf[2][2];
#pragma unroll
  for (int mi = 0; mi < 2; ++mi)
#pragma unroll
    for (int ks = 0; ks < 2; ++ks)
      qf[mi][ks] = *(const bh8*)(Qb + baseq + (size_t)(q0 + wave * 32 + mi * 16 + l15) * 1024 + ks * 32 + quad * 8);

  f4 O[2][4];
  float l_part[2] = {0.f, 0.f};
#pragma unroll
  for (int mi = 0; mi < 2; ++mi)
#pragma unroll
    for (int di = 0; di < 4; ++di) O[mi][di] = (f4){0.f, 0.f, 0.f, 0.f};

  for (int kt = 0; kt < 2048; kt += 64) {
    __syncthreads();  // prior tile's LDS reads done
    // stage K tile: chunk c -> (kk=c>>3, dq=(c&7)^(kk&7))
#pragma unroll
    for (int i = 0; i < 2; ++i) {
      int c = i * 256 + t;
      int kk = c >> 3;
      int dq = (c & 7) ^ (kk & 7);
      async16(Kb + baseq + (size_t)(kt + kk) * 1024 + dq * 8,
              (char*)k_lds + (i * 256 + wave * 64) * 16);
    }
    // stage V^T tile: chunk c -> (d=c>>3, kc=(c&7)^(d&7)); rows of VT are t-contiguous
#pragma unroll
    for (int i = 0; i < 2; ++i) {
      int c = i * 256 + t;
      int d = c >> 3;
      int kc = (c & 7) ^ (d & 7);
      async16(VTb + basev + (size_t)d * 8192 + kt + kc * 8,
              (char*)vt_lds + (i * 256 + wave * 64) * 16);
    }
    __syncthreads();  // staging complete (drains vmcnt)

    // S^T - 16 = K Q^T - 16 (C-init carries the static bound)
    f4 ST[4][2];
#pragma unroll
    for (int mK = 0; mK < 4; ++mK) {
      int key = mK * 16 + l15;
      bh8 ka0 = *(const bh8*)(k_lds + (key * 8 + (quad ^ (key & 7))) * 8);
      bh8 ka1 = *(const bh8*)(k_lds + (key * 8 + ((quad + 4) ^ (key & 7))) * 8);
#pragma unroll
      for (int mi = 0; mi < 2; ++mi) {
        f4 s = (f4){-16.f, -16.f, -16.f, -16.f};
        s = __builtin_amdgcn_mfma_f32_16x16x32_bf16(ka0, qf[mi][0], s, 0, 0, 0);
        s = __builtin_amdgcn_mfma_f32_16x16x32_bf16(ka1, qf[mi][1], s, 0, 0, 0);
        ST[mK][mi] = s;
      }
    }

    // p = exp2(ST), accumulate per-lane l partials, pack to bf16, LDS round-trip.
    // mi halves time-share the 16-row p_lds buffer (same-wave DS ops are in-order).
    bh8 pa[2][2];
#pragma unroll
    for (int mi = 0; mi < 2; ++mi) {
      float lp = 0.f;
#pragma unroll
      for (int mK = 0; mK < 4; ++mK) {
        float p0 = EXP2(ST[mK][mi][0]);
        float p1 = EXP2(ST[mK][mi][1]);
        float p2 = EXP2(ST[mK][mi][2]);
        float p3 = EXP2(ST[mK][mi][3]);
        lp += (p0 + p1) + (p2 + p3);
        u32 d0 = __builtin_amdgcn_perm(__float_as_uint(p1), __float_as_uint(p0), 0x07060302u);
        u32 d1 = __builtin_amdgcn_perm(__float_as_uint(p3), __float_as_uint(p2), 0x07060302u);
        u32x2 dd = {d0, d1};
        *(u32x2*)(&p_lds[wave][l15 * 72 + mK * 16 + quad * 4]) = dd;
      }
      l_part[mi] += lp;
#pragma unroll
      for (int ks = 0; ks < 2; ++ks)
        pa[mi][ks] = *(const bh8*)(&p_lds[wave][l15 * 72 + ks * 32 + quad * 8]);
    }

    // O += P V
#pragma unroll
    for (int di = 0; di < 4; ++di) {
      int d = di * 16 + l15;
      bh8 vb0 = *(const bh8*)(vt_lds + (d * 8 + (quad ^ (d & 7))) * 8);
      bh8 vb1 = *(const bh8*)(vt_lds + (d * 8 + ((quad + 4) ^ (d & 7))) * 8);
#pragma unroll
      for (int mi = 0; mi < 2; ++mi) {
        f4 o = O[mi][di];
        o = __builtin_amdgcn_mfma_f32_16x16x32_bf16(pa[mi][0], vb0, o, 0, 0, 0);
        o = __builtin_amdgcn_mfma_f32_16x16x32_bf16(pa[mi][1], vb1, o, 0, 0, 0);
        O[mi][di] = o;
      }
    }
  }

  // epilogue: reduce l across quads (lanes sharing l15), broadcast 1/l to O rows, store
#pragma unroll
  for (int mi = 0; mi < 2; ++mi) {
    float l0 = l_part[mi];
    l0 += __shfl_xor(l0, 16);
    l0 += __shfl_xor(l0, 32);
    float rl[4];
#pragma unroll
    for (int r = 0; r < 4; ++r) {
      float lb = __shfl(l0, quad * 4 + r);
      rl[r] = __builtin_amdgcn_rcpf(lb);
    }
#pragma unroll
    for (int di = 0; di < 4; ++di)
#pragma unroll
      for (int r = 0; r < 4; ++r) {
        int row = q0 + wave * 32 + mi * 16 + quad * 4 + r;
        AO[baseq + (size_t)row * 1024 + di * 16 + l15] = f2bf(O[mi][di][r] * rl[r]);
      }
  }
}

// ---------------- launch ----------------
extern "C" void kernel_launch(void* const* d_in, const int* in_sizes, int n_in,
                              void* d_out, int out_size, void* d_ws, size_t ws_size,
                              hipStream_t stream) {
  const float* x  = (const float*)d_in[0];
  const float* Wq = (const float*)d_in[1];
  const float* bq = (const float*)d_in[2];
  const float* Wk = (const float*)d_in[3];
  const float* bk = (const float*)d_in[4];
  const float* Wv = (const float*)d_in[5];
  const float* bv = (const float*)d_in[6];
  const float* Wo = (const float*)d_in[7];
  const float* bo = (const float*)d_in[8];
  float* out = (float*)d_out;

  const int M = 8192, E = 1024;
  const size_t NX = (size_t)M * E;
  const size_t NW = (size_t)E * E;

  short* ws  = (short*)d_ws;
  short* xb  = ws;            // x bf16 [M][E]
  short* wqb = xb + NX;       // weights contiguous: wq, wk, wv, wo
  short* wob = wqb + 3 * NW;
  short* qb  = wob + NW;      // Q bf16 (pre-scaled by log2e/8)
  short* kb  = qb + NX;
  short* vt  = kb + NX;       // V^T bf16 [E][M] (t-contiguous rows)
  short* aob = xb;            // attention output aliases xb (xb dead after QKV GEMM)

  // fused convert: (NX + 4*NW)/4 f4-groups / 256 threads = 12288 blocks exactly
  cvt_all<<<dim3(12288), 256, 0, stream>>>(x, Wq, Wk, Wv, Wo, xb, wqb);

  const float qscale = 0.18033688011112042f;  // log2(e) / sqrt(64)
  gemm_qkv<<<dim3(24, 64), 256, 0, stream>>>(xb, wqb, bq, bk, bv, qb, kb, vt, qscale);

  attn_kernel<<<dim3(16, 64), 256, 0, stream>>>(qb, kb, vt, aob);

  gemm_bt_f32<<<dim3(8, 64), 256, 0, stream>>>(aob, wob, bo, out);
}